// Round 1
// baseline (283.110 us; speedup 1.0000x reference)
//
#include <hip/hip_runtime.h>
#include <hip/hip_bf16.h>

#define DIM_IN  128
#define DIM_OUT 64

// ---------------------------------------------------------------------------
// K1: h = x @ W   (fp32 GEMM, N x 128 @ 128 x 64)
// One wave (64 lanes) per output row; lane = output column.
// W (128*64 fp32 = 32 KB) staged in LDS once per block.
// ---------------------------------------------------------------------------
__global__ __launch_bounds__(256) void gnn_gemm_kernel(
    const float* __restrict__ x,   // [N, 128]
    const float* __restrict__ W,   // [128, 64]
    float* __restrict__ h,         // [N, 64]
    int n_nodes)
{
    __shared__ float Ws[DIM_IN * DIM_OUT];  // 32 KiB
    for (int i = threadIdx.x; i < DIM_IN * DIM_OUT; i += blockDim.x)
        Ws[i] = W[i];
    __syncthreads();

    const int tid = blockIdx.x * blockDim.x + threadIdx.x;
    const int row = tid >> 6;   // wave per row
    const int col = tid & 63;   // lane per column
    if (row >= n_nodes) return;

    const float* xr = x + (size_t)row * DIM_IN;
    float sum = 0.0f;
    // x reads are lane-uniform (broadcast); Ws reads conflict-free
    // (64 consecutive floats -> 2 lanes/bank, free per G4).
    #pragma unroll
    for (int k = 0; k < DIM_IN; k += 4) {
        float4 xv = *reinterpret_cast<const float4*>(xr + k);
        sum += xv.x * Ws[(k + 0) * DIM_OUT + col];
        sum += xv.y * Ws[(k + 1) * DIM_OUT + col];
        sum += xv.z * Ws[(k + 2) * DIM_OUT + col];
        sum += xv.w * Ws[(k + 3) * DIM_OUT + col];
    }
    h[(size_t)row * DIM_OUT + col] = sum;
}

// ---------------------------------------------------------------------------
// K2: out[r] += adj_vals[e] * h[c]  for each edge e=(r,c)
// One thread per (edge, dim). Lanes 0..63 of a wave cover the 64 dims of a
// single edge -> gather + atomics land on consecutive addresses.
// ---------------------------------------------------------------------------
__global__ __launch_bounds__(256) void gnn_scatter_kernel(
    const float* __restrict__ h,          // [N, 64]
    const int*   __restrict__ edge_rows,  // [E]
    const int*   __restrict__ edge_cols,  // [E]
    const float* __restrict__ adj_vals,   // [E]
    float* __restrict__ out,              // [N, 64]
    int n_edges)
{
    const long long idx   = (long long)blockIdx.x * blockDim.x + threadIdx.x;
    const long long total = (long long)n_edges * DIM_OUT;
    if (idx >= total) return;

    const int e = (int)(idx >> 6);
    const int d = (int)(idx & 63);

    // lane-uniform scalar reads per edge (broadcast within the wave)
    const int   r = edge_rows[e];
    const int   c = edge_cols[e];
    const float a = adj_vals[e];

    const float v = a * h[(size_t)c * DIM_OUT + d];
    atomicAdd(&out[(size_t)r * DIM_OUT + d], v);  // device-scope on CDNA
}

extern "C" void kernel_launch(void* const* d_in, const int* in_sizes, int n_in,
                              void* d_out, int out_size, void* d_ws, size_t ws_size,
                              hipStream_t stream)
{
    const float* x         = (const float*)d_in[0];  // [N, 128]
    const float* W         = (const float*)d_in[1];  // [128, 64]
    const int*   edge_rows = (const int*)d_in[2];    // [E]
    const int*   edge_cols = (const int*)d_in[3];    // [E]
    const float* adj_vals  = (const float*)d_in[4];  // [E]
    float*       out       = (float*)d_out;          // [N, 64]

    const int n_nodes = in_sizes[0] / DIM_IN;
    const int n_edges = in_sizes[2];

    float* h = (float*)d_ws;  // [N, 64] scratch: 50000*64*4 = 12.8 MB

    // Zero the (poisoned) output accumulator. Memset nodes are
    // graph-capture-safe stream ops.
    hipMemsetAsync(d_out, 0, (size_t)out_size * sizeof(float), stream);

    // K1: dense transform
    {
        const int threads = 256;                     // 4 waves = 4 rows/block
        const int rows_per_block = threads / 64;
        const int grid = (n_nodes + rows_per_block - 1) / rows_per_block;
        gnn_gemm_kernel<<<grid, threads, 0, stream>>>(x, W, h, n_nodes);
    }

    // K2: gather-scale-scatter
    {
        const long long total = (long long)n_edges * DIM_OUT;
        const int threads = 256;
        const long long grid = (total + threads - 1) / threads;
        gnn_scatter_kernel<<<(int)grid, threads, 0, stream>>>(
            h, edge_rows, edge_cols, adj_vals, out, n_edges);
    }
}